// Round 12
// baseline (501.327 us; speedup 1.0000x reference)
//
#include <hip/hip_runtime.h>
#include <hip/hip_bf16.h>
#include <stdint.h>

#define IN_F 4096
#define OUT_F 4096
#define M_TOTAL 8192   // 4 * 2048
#define NKT 64         // IN_F / 64

typedef __hip_bfloat16 bf16;
typedef __attribute__((ext_vector_type(8))) short bf16x8;   // 8 bf16 (4 VGPRs)
typedef __attribute__((ext_vector_type(4))) float f32x4;    // MFMA accumulator

// ---------------- kernel 1: fused prep — dequant W (blocks [0,8192)) + cvt x (rest)
__global__ __launch_bounds__(256) void prep(const int* __restrict__ qweight,
                                            const float* __restrict__ scales,
                                            const int* __restrict__ qzeros,
                                            bf16* __restrict__ Wb,
                                            const float* __restrict__ x,
                                            bf16* __restrict__ Xb) {
    int b = blockIdx.x;
    if (b < 8192) {
        int idx = b * 256 + threadIdx.x;            // one int32 (8 nibbles) per thread
        int o = idx >> 9;                           // / (IN_F/8)
        int j = idx & 511;
        int g = j >> 4;                             // (j*8)/128
        int qw = qweight[idx];
        float s = scales[g * OUT_F + o];
        float z = (float)qzeros[g * OUT_F + o];
        union { bf16 h[8]; uint4 q; } out;
#pragma unroll
        for (int k = 0; k < 8; ++k) {
            float w = (float)((qw >> (4 * k)) & 15);
            out.h[k] = __float2bfloat16((w - z) * s);
        }
        *reinterpret_cast<uint4*>(Wb + ((size_t)o * IN_F + j * 8)) = out.q;
    } else {
        int idx = (b - 8192) * 256 + threadIdx.x;   // 8 floats per thread
        const float4* p = reinterpret_cast<const float4*>(x) + (size_t)idx * 2;
        float4 a = p[0], c = p[1];
        union { bf16 h[8]; uint4 q; } o;
        o.h[0] = __float2bfloat16(a.x); o.h[1] = __float2bfloat16(a.y);
        o.h[2] = __float2bfloat16(a.z); o.h[3] = __float2bfloat16(a.w);
        o.h[4] = __float2bfloat16(c.x); o.h[5] = __float2bfloat16(c.y);
        o.h[6] = __float2bfloat16(c.z); o.h[7] = __float2bfloat16(c.w);
        reinterpret_cast<uint4*>(Xb)[idx] = o.q;
    }
}

// ---------------- kernel 2: 256x256 8-phase bf16 GEMM, DEPTH-2 fragment pre-reads.
// From round-10's single-barrier 8-phase (230us).  Reads for phase P issue at
// P-2; phase-start waits are counted lgkmcnt(R_prev) so they only cover >=2-
// phase-old reads (~free).  Per-phase vmcnt(4) keeps the 2 newest stage-pairs
// in flight and drains everything older before that phase's pre-reads.
// Fragment double-buffer: af0A/B (MH0), af1A/B (MH1), bfr0A/B (NH0), bfr1A/B (NH1).
// Phase->regs: P1(af0A,bfr0A) P2(af1A,bfr0A) P3(af0A,bfr1A) P4(af1A,bfr1A)
//              P5(af0B,bfr0B) P6(af1B,bfr0B) P7(af0B,bfr1B) P8(af1B,bfr1B)
// Pre-read issues: P1:bfr1A(4) P3:af0B+bfr0B(12) P4:af1B(8) P5:bfr1B(4)
//                  P7:af0A+bfr0A(12,gg) P8:af1A(8,gg)   -> lgkm counts 8,4,0,12,...
// Stage regions (same as round-10; region read-free >=1 barrier before stage):
//  P1 buf1.Bh1(t1) P2 buf0.Ah0(t2) P3 buf0.Ah1 P4 buf0.Bh0 P5 buf0.Bh1
//  P6 buf1.Ah0(t3) P7 buf1.Ah1 P8 buf1.Bh0
// C(MxN) = A(MxK)*B(NxK)^T + bias. 8 waves (2M x 4N), per-wave 128x64 out.
// LDS 128 KiB: buf b at b*65536; A h0/h1 @ +0/+16384, B h0/h1 @ +32768/+49152.
// Swizzle: 16B slot s of row r stored at s ^ (r & 7); pre-swizzled global src.

__device__ __forceinline__ void gload16(const bf16* g, char* l) {
    __builtin_amdgcn_global_load_lds(
        (const __attribute__((address_space(1))) void*)g,
        (__attribute__((address_space(3))) void*)l, 16, 0, 0);
}

// Stage 128 rows x 64 cols bf16 (16 KiB): 8 waves x 2 loads x 64 lanes x 16 B.
__device__ __forceinline__ void stage_half(const bf16* __restrict__ Gt,
                                           char* ldsb, int wave, int lane) {
    const int slog8 = ((lane & 7) ^ (lane >> 3)) * 8;   // pre-swizzled 16B slot
#pragma unroll
    for (int j = 0; j < 2; ++j) {
        int r = wave * 16 + j * 8 + (lane >> 3);        // r & 7 == lane>>3
        gload16(Gt + (size_t)r * IN_F + slog8, ldsb + (wave * 2 + j) * 1024);
    }
}

#define BARRIER() do { asm volatile("" ::: "memory"); \
                       __builtin_amdgcn_s_barrier();  \
                       asm volatile("" ::: "memory"); } while (0)
#define LGKM0()   asm volatile("s_waitcnt lgkmcnt(0)"  ::: "memory")
#define LGKM4()   asm volatile("s_waitcnt lgkmcnt(4)"  ::: "memory")
#define LGKM8()   asm volatile("s_waitcnt lgkmcnt(8)"  ::: "memory")
#define LGKM12()  asm volatile("s_waitcnt lgkmcnt(12)" ::: "memory")
#define VMCNT6()  asm volatile("s_waitcnt vmcnt(6)" ::: "memory")
#define VMCNT4()  asm volatile("s_waitcnt vmcnt(4)" ::: "memory")
#define VMCNT0()  asm volatile("s_waitcnt vmcnt(0)" ::: "memory")

// A fragment rows: MH*128 + wr*64 + m4*16 + l15 (af reads only Ah<MH> region)
#define LDA_SET(DST, BUF, MH) do {                                              \
  _Pragma("unroll") for (int m4 = 0; m4 < 4; ++m4)                              \
  _Pragma("unroll") for (int kk = 0; kk < 2; ++kk)                              \
    DST[m4][kk] = *reinterpret_cast<const bf16x8*>(sm + (BUF) * 65536           \
        + (((MH) * 128 + wr * 64 + m4 * 16 + l15) << 7)                         \
        + ((((kk << 2) + lq) ^ l7) << 4));                                      \
} while (0)

// B fragment rows: NH*128 + wc*32 + n2*16 + l15 (bfr reads only Bh<NH> region)
#define LDB_SET(DST, BUF, NH) do {                                              \
  _Pragma("unroll") for (int n2 = 0; n2 < 2; ++n2)                              \
  _Pragma("unroll") for (int kk = 0; kk < 2; ++kk)                              \
    DST[n2][kk] = *reinterpret_cast<const bf16x8*>(sm + (BUF) * 65536 + 32768   \
        + (((NH) * 128 + wc * 32 + n2 * 16 + l15) << 7)                         \
        + ((((kk << 2) + lq) ^ l7) << 4));                                      \
} while (0)

#define MMA_Q(AF, BFR, MH, NH) do {                                             \
  __builtin_amdgcn_s_setprio(1);                                                \
  _Pragma("unroll") for (int m4 = 0; m4 < 4; ++m4)                              \
  _Pragma("unroll") for (int n2 = 0; n2 < 2; ++n2)                              \
  _Pragma("unroll") for (int kk = 0; kk < 2; ++kk)                              \
    acc[(MH) * 4 + m4][(NH) * 2 + n2] = __builtin_amdgcn_mfma_f32_16x16x32_bf16(\
        AF[m4][kk], BFR[n2][kk], acc[(MH) * 4 + m4][(NH) * 2 + n2], 0, 0, 0);   \
  __builtin_amdgcn_s_setprio(0);                                                \
} while (0)

__global__ __launch_bounds__(512, 2) void gemm256(const bf16* __restrict__ A,   // M x K
                                                  const bf16* __restrict__ B,   // N x K
                                                  const float* __restrict__ bias,
                                                  float* __restrict__ C) {
    extern __shared__ char sm[];
    const int tid  = threadIdx.x;
    const int wave = tid >> 6;
    const int lane = tid & 63;
    const int wr   = wave >> 2;       // 2 M-rows of waves
    const int wc   = wave & 3;        // 4 N-cols of waves
    const int l15  = lane & 15;
    const int lq   = lane >> 4;
    const int l7   = lane & 7;

    // XCD-aware bijective swizzle (nwg = 512, % 8 == 0)
    const int nwg = gridDim.x;
    const int cpx = nwg >> 3;
    const int wg  = blockIdx.x;
    const int swz = (wg & 7) * cpx + (wg >> 3);
    const int bm  = swz >> 4;         // 16 n-tiles (4096/256)
    const int bn  = swz & 15;
    const int m0  = bm * 256;
    const int n0  = bn * 256;

    const bf16* A0 = A + (size_t)m0 * IN_F;          // A h0 rows
    const bf16* A1 = A + (size_t)(m0 + 128) * IN_F;  // A h1 rows
    const bf16* B0 = B + (size_t)n0 * IN_F;
    const bf16* B1 = B + (size_t)(n0 + 128) * IN_F;

    f32x4 acc[8][4];
#pragma unroll
    for (int m = 0; m < 8; ++m)
#pragma unroll
        for (int n = 0; n < 4; ++n) acc[m][n] = (f32x4){0.f, 0.f, 0.f, 0.f};

    bf16x8 af0A[4][2], af1A[4][2], af0B[4][2], af1B[4][2];
    bf16x8 bfr0A[2][2], bfr1A[2][2], bfr0B[2][2], bfr1B[2][2];

    // ---- prologue: t0 fully (buf0) + t1 {Ah0,Ah1,Bh0} (buf1); 14 loads/wave
    stage_half(A0,      sm + 0,     wave, lane);   // t0 Ah0
    stage_half(A1,      sm + 16384, wave, lane);   // t0 Ah1
    stage_half(B0,      sm + 32768, wave, lane);   // t0 Bh0
    stage_half(B1,      sm + 49152, wave, lane);   // t0 Bh1
    stage_half(A0 + 64, sm + 65536, wave, lane);   // t1 Ah0
    stage_half(A1 + 64, sm + 81920, wave, lane);   // t1 Ah1
    stage_half(B0 + 64, sm + 98304, wave, lane);   // t1 Bh0
    VMCNT6();          // t0 drained; t1's 3 halves stay in flight
    BARRIER();
    LDA_SET(af0A, 0, 0);          // ≡ prev-P7 issues (12 reads)
    LDB_SET(bfr0A, 0, 0);
    LDA_SET(af1A, 0, 1);          // ≡ prev-P8 issues (8 reads)

    for (int i = 0; i < 32; ++i) {
        const int t1 = 2 * i + 1;
        const int t2 = 2 * i + 2;
        const int t3 = 2 * i + 3;
        const bool gg = (i < 31);

        // ---- P1: t0 (MH0,NH0)
        stage_half(B1 + t1 * 64, sm + 114688, wave, lane);   // buf1.Bh1(t1)
        LGKM8();                         // waits af0A,bfr0A (2 phases old)
        MMA_Q(af0A, bfr0A, 0, 0);
        VMCNT4();
        LDB_SET(bfr1A, 0, 1);            // for P3
        BARRIER();
        // ---- P2: (MH1,NH0)
        if (gg) stage_half(A0 + t2 * 64, sm + 0, wave, lane);      // buf0.Ah0(t2)
        LGKM4();                         // waits af1A
        MMA_Q(af1A, bfr0A, 1, 0);
        VMCNT4();
        BARRIER();
        // ---- P3: (MH0,NH1)
        if (gg) stage_half(A1 + t2 * 64, sm + 16384, wave, lane);  // buf0.Ah1(t2)
        LGKM0();                         // waits bfr1A
        MMA_Q(af0A, bfr1A, 0, 1);
        if (gg) { VMCNT4(); } else { VMCNT0(); }  // tail: drain P1's Bh1 stager
        LDA_SET(af0B, 1, 0);             // for P5
        LDB_SET(bfr0B, 1, 0);
        BARRIER();
        // ---- P4: (MH1,NH1)
        if (gg) stage_half(B0 + t2 * 64, sm + 32768, wave, lane);  // buf0.Bh0(t2)
        LGKM12();
        MMA_Q(af1A, bfr1A, 1, 1);
        VMCNT4();
        LDA_SET(af1B, 1, 1);             // for P6
        BARRIER();

        // ---- P5: t1 (buf1) (MH0,NH0)
        if (gg) stage_half(B1 + t2 * 64, sm + 49152, wave, lane);  // buf0.Bh1(t2)
        LGKM8();                         // waits af0B,bfr0B
        MMA_Q(af0B, bfr0B, 0, 0);
        VMCNT4();
        LDB_SET(bfr1B, 1, 1);            // for P7
        BARRIER();
        // ---- P6: (MH1,NH0)
        if (gg) stage_half(A0 + t3 * 64, sm + 65536, wave, lane);  // buf1.Ah0(t3)
        LGKM4();                         // waits af1B
        MMA_Q(af1B, bfr0B, 1, 0);
        VMCNT4();
        BARRIER();
        // ---- P7: (MH0,NH1)
        if (gg) stage_half(A1 + t3 * 64, sm + 81920, wave, lane);  // buf1.Ah1(t3)
        LGKM0();                         // waits bfr1B
        MMA_Q(af0B, bfr1B, 0, 1);
        VMCNT4();
        if (gg) { LDA_SET(af0A, 0, 0); LDB_SET(bfr0A, 0, 0); }     // for next P1
        BARRIER();
        // ---- P8: (MH1,NH1)
        if (gg) stage_half(B0 + t3 * 64, sm + 98304, wave, lane);  // buf1.Bh0(t3)
        LGKM12();
        MMA_Q(af1B, bfr1B, 1, 1);
        VMCNT4();
        if (gg) LDA_SET(af1A, 0, 1);     // for next P2
        BARRIER();
    }

    // ---- epilogue: C/D layout col = lane&15, row = (lane>>4)*4 + reg
    const int crow_base = m0 + wr * 64 + lq * 4;
    const int ccol_base = n0 + wc * 32 + l15;
#pragma unroll
    for (int n = 0; n < 4; ++n) {
        const int NH = n >> 1, n2 = n & 1;
        const int col = ccol_base + NH * 128 + n2 * 16;
        float bv = bias[col];
#pragma unroll
        for (int m = 0; m < 8; ++m) {
            const int MH = m >> 2, m4 = m & 3;
            const int row = crow_base + MH * 128 + m4 * 16;
#pragma unroll
            for (int r = 0; r < 4; ++r)
                C[(size_t)(row + r) * OUT_F + col] = acc[m][n][r] + bv;
        }
    }
}

// ---------------- fallback: fp32 tiled GEMM with on-the-fly dequant (ws too small)
__global__ __launch_bounds__(256) void fallback_gemm(const float* __restrict__ x,
                                                     const int* __restrict__ qweight,
                                                     const float* __restrict__ scales,
                                                     const int* __restrict__ qzeros,
                                                     const float* __restrict__ bias,
                                                     float* __restrict__ out) {
    __shared__ float Asf[64][65];
    __shared__ float Bsf[64][65];
    int bm = blockIdx.x >> 6;
    int bn = blockIdx.x & 63;
    int m0 = bm * 64, n0 = bn * 64;
    int t  = threadIdx.x;
    int tr = t >> 4, tc = t & 15;
    float acc[4][4] = {};
    for (int kt = 0; kt < IN_F; kt += 64) {
#pragma unroll
        for (int i = 0; i < 4; ++i) {
            int idx = t + i * 256;
            int r = idx >> 4, c4 = idx & 15;
            float4 v = *reinterpret_cast<const float4*>(x + (size_t)(m0 + r) * IN_F + kt + c4 * 4);
            Asf[r][c4 * 4 + 0] = v.x; Asf[r][c4 * 4 + 1] = v.y;
            Asf[r][c4 * 4 + 2] = v.z; Asf[r][c4 * 4 + 3] = v.w;
        }
#pragma unroll
        for (int i = 0; i < 2; ++i) {
            int idx = t + i * 256;
            int r = idx >> 3, k8 = idx & 7;
            int kk = kt + k8 * 8;
            int o  = n0 + r;
            int qw = qweight[(size_t)o * (IN_F / 8) + (kk >> 3)];
            int g  = kk >> 7;
            float s = scales[g * OUT_F + o];
            float z = (float)qzeros[g * OUT_F + o];
#pragma unroll
            for (int b = 0; b < 8; ++b)
                Bsf[r][k8 * 8 + b] = ((float)((qw >> (4 * b)) & 15) - z) * s;
        }
        __syncthreads();
#pragma unroll 8
        for (int k = 0; k < 64; ++k) {
            float a[4], bb[4];
#pragma unroll
            for (int i = 0; i < 4; ++i) a[i] = Asf[tr * 4 + i][k];
#pragma unroll
            for (int j = 0; j < 4; ++j) bb[j] = Bsf[tc * 4 + j][k];
#pragma unroll
            for (int i = 0; i < 4; ++i)
#pragma unroll
                for (int j = 0; j < 4; ++j) acc[i][j] += a[i] * bb[j];
        }
        __syncthreads();
    }
#pragma unroll
    for (int i = 0; i < 4; ++i) {
        int row = m0 + tr * 4 + i;
#pragma unroll
        for (int j = 0; j < 4; ++j) {
            int col = n0 + tc * 4 + j;
            out[(size_t)row * OUT_F + col] = acc[i][j] + bias[col];
        }
    }
}

extern "C" void kernel_launch(void* const* d_in, const int* in_sizes, int n_in,
                              void* d_out, int out_size, void* d_ws, size_t ws_size,
                              hipStream_t stream) {
    (void)in_sizes; (void)n_in; (void)out_size;
    const float* x       = (const float*)d_in[0];
    const int*   qweight = (const int*)d_in[1];
    const float* scales  = (const float*)d_in[2];
    const int*   qzeros  = (const int*)d_in[3];
    const float* bias    = (const float*)d_in[4];
    float* out = (float*)d_out;

    const size_t needW = (size_t)OUT_F * IN_F * sizeof(bf16);   // 32 MB
    const size_t needX = (size_t)M_TOTAL * IN_F * sizeof(bf16); // 64 MB

    if (ws_size >= needW + needX) {
        bf16* Wb = (bf16*)d_ws;
        bf16* Xb = (bf16*)((char*)d_ws + needW);
        // fused prep: 8192 dequant blocks + 16384 cvt blocks
        prep<<<8192 + 16384, 256, 0, stream>>>(qweight, scales, qzeros, Wb, x, Xb);
        gemm256<<<(M_TOTAL / 256) * (OUT_F / 256), 512, 131072, stream>>>(Xb, Wb, bias, out);
    } else {
        fallback_gemm<<<(M_TOTAL / 64) * (OUT_F / 64), 256, 0, stream>>>(
            x, qweight, scales, qzeros, bias, out);
    }
}

// Round 13
// 269.883 us; speedup vs baseline: 1.8576x; 1.8576x over previous
//
#include <hip/hip_runtime.h>
#include <hip/hip_bf16.h>
#include <stdint.h>

#define IN_F 4096
#define OUT_F 4096
#define M_TOTAL 8192   // 4 * 2048
#define NKT 64         // IN_F / 64

typedef __hip_bfloat16 bf16;
typedef __attribute__((ext_vector_type(8))) short bf16x8;   // 8 bf16 (4 VGPRs)
typedef __attribute__((ext_vector_type(4))) float f32x4;    // MFMA accumulator

// ---------------- kernel 1: fused prep — dequant W (blocks [0,8192)) + cvt x (rest)
__global__ __launch_bounds__(256) void prep(const int* __restrict__ qweight,
                                            const float* __restrict__ scales,
                                            const int* __restrict__ qzeros,
                                            bf16* __restrict__ Wb,
                                            const float* __restrict__ x,
                                            bf16* __restrict__ Xb) {
    int b = blockIdx.x;
    if (b < 8192) {
        int idx = b * 256 + threadIdx.x;            // one int32 (8 nibbles) per thread
        int o = idx >> 9;                           // / (IN_F/8)
        int j = idx & 511;
        int g = j >> 4;                             // (j*8)/128
        int qw = qweight[idx];
        float s = scales[g * OUT_F + o];
        float z = (float)qzeros[g * OUT_F + o];
        union { bf16 h[8]; uint4 q; } out;
#pragma unroll
        for (int k = 0; k < 8; ++k) {
            float w = (float)((qw >> (4 * k)) & 15);
            out.h[k] = __float2bfloat16((w - z) * s);
        }
        *reinterpret_cast<uint4*>(Wb + ((size_t)o * IN_F + j * 8)) = out.q;
    } else {
        int idx = (b - 8192) * 256 + threadIdx.x;   // 8 floats per thread
        const float4* p = reinterpret_cast<const float4*>(x) + (size_t)idx * 2;
        float4 a = p[0], c = p[1];
        union { bf16 h[8]; uint4 q; } o;
        o.h[0] = __float2bfloat16(a.x); o.h[1] = __float2bfloat16(a.y);
        o.h[2] = __float2bfloat16(a.z); o.h[3] = __float2bfloat16(a.w);
        o.h[4] = __float2bfloat16(c.x); o.h[5] = __float2bfloat16(c.y);
        o.h[6] = __float2bfloat16(c.z); o.h[7] = __float2bfloat16(c.w);
        reinterpret_cast<uint4*>(Xb)[idx] = o.q;
    }
}

// ---------------- kernel 2: 256x256 8-phase bf16 GEMM — round-10 proven state.
// Single barrier per phase (ledger-verified: every stage >=2 barriers after its
// region's last pre-read); 1-phase-ahead ds_read pre-reads; counted vmcnt(6);
// setprio around MFMA; XCD-bijective block swizzle; conflict-free XOR swizzle.
// C(MxN) = A(MxK)*B(NxK)^T + bias. 8 waves (2M x 4N), per-wave 128x64 out.
// Fragment rows: A = MH*128 + wr*64 + m4*16; B = NH*128 + wc*32 + n2*16.
// LDS 128 KiB: buf b at b*65536; A h0/h1 @ +0/+16384, B h0/h1 @ +32768/+49152.
// Swizzle: 16B slot s of row r stored at s ^ (r & 7); pre-swizzled global src.

__device__ __forceinline__ void gload16(const bf16* g, char* l) {
    __builtin_amdgcn_global_load_lds(
        (const __attribute__((address_space(1))) void*)g,
        (__attribute__((address_space(3))) void*)l, 16, 0, 0);
}

// Stage 128 rows x 64 cols bf16 (16 KiB): 8 waves x 2 loads x 64 lanes x 16 B.
__device__ __forceinline__ void stage_half(const bf16* __restrict__ Gt,
                                           char* ldsb, int wave, int lane) {
    const int slog8 = ((lane & 7) ^ (lane >> 3)) * 8;   // pre-swizzled 16B slot
#pragma unroll
    for (int j = 0; j < 2; ++j) {
        int r = wave * 16 + j * 8 + (lane >> 3);        // r & 7 == lane>>3
        gload16(Gt + (size_t)r * IN_F + slog8, ldsb + (wave * 2 + j) * 1024);
    }
}

#define BARRIER() do { asm volatile("" ::: "memory"); \
                       __builtin_amdgcn_s_barrier();  \
                       asm volatile("" ::: "memory"); } while (0)
#define LGKM0()   asm volatile("s_waitcnt lgkmcnt(0)" ::: "memory")
#define VMCNT6()  asm volatile("s_waitcnt vmcnt(6)" ::: "memory")
#define VMCNT0()  asm volatile("s_waitcnt vmcnt(0)" ::: "memory")

// A fragment rows: MH*128 + wr*64 + m4*16 + l15
#define LDA_SET(DST, BUF, MH) do {                                              \
  _Pragma("unroll") for (int m4 = 0; m4 < 4; ++m4)                              \
  _Pragma("unroll") for (int kk = 0; kk < 2; ++kk)                              \
    DST[m4][kk] = *reinterpret_cast<const bf16x8*>(sm + (BUF) * 65536           \
        + (((MH) * 128 + wr * 64 + m4 * 16 + l15) << 7)                         \
        + ((((kk << 2) + lq) ^ l7) << 4));                                      \
} while (0)

// B fragment rows: NH*128 + wc*32 + n2*16 + l15
#define LDB_SET(DST, BUF, NH) do {                                              \
  _Pragma("unroll") for (int n2 = 0; n2 < 2; ++n2)                              \
  _Pragma("unroll") for (int kk = 0; kk < 2; ++kk)                              \
    DST[n2][kk] = *reinterpret_cast<const bf16x8*>(sm + (BUF) * 65536 + 32768   \
        + (((NH) * 128 + wc * 32 + n2 * 16 + l15) << 7)                         \
        + ((((kk << 2) + lq) ^ l7) << 4));                                      \
} while (0)

#define MMA_Q(AF, BFR, MH, NH) do {                                             \
  __builtin_amdgcn_s_setprio(1);                                                \
  _Pragma("unroll") for (int m4 = 0; m4 < 4; ++m4)                              \
  _Pragma("unroll") for (int n2 = 0; n2 < 2; ++n2)                              \
  _Pragma("unroll") for (int kk = 0; kk < 2; ++kk)                              \
    acc[(MH) * 4 + m4][(NH) * 2 + n2] = __builtin_amdgcn_mfma_f32_16x16x32_bf16(\
        AF[m4][kk], BFR[n2][kk], acc[(MH) * 4 + m4][(NH) * 2 + n2], 0, 0, 0);   \
  __builtin_amdgcn_s_setprio(0);                                                \
} while (0)

__global__ __launch_bounds__(512, 2) void gemm256(const bf16* __restrict__ A,   // M x K
                                                  const bf16* __restrict__ B,   // N x K
                                                  const float* __restrict__ bias,
                                                  float* __restrict__ C) {
    extern __shared__ char sm[];
    const int tid  = threadIdx.x;
    const int wave = tid >> 6;
    const int lane = tid & 63;
    const int wr   = wave >> 2;       // 2 M-rows of waves
    const int wc   = wave & 3;        // 4 N-cols of waves
    const int l15  = lane & 15;
    const int lq   = lane >> 4;
    const int l7   = lane & 7;

    // XCD-aware bijective swizzle (nwg = 512, % 8 == 0)
    const int nwg = gridDim.x;
    const int cpx = nwg >> 3;
    const int wg  = blockIdx.x;
    const int swz = (wg & 7) * cpx + (wg >> 3);
    const int bm  = swz >> 4;         // 16 n-tiles (4096/256)
    const int bn  = swz & 15;
    const int m0  = bm * 256;
    const int n0  = bn * 256;

    const bf16* A0 = A + (size_t)m0 * IN_F;          // A h0 rows
    const bf16* A1 = A + (size_t)(m0 + 128) * IN_F;  // A h1 rows
    const bf16* B0 = B + (size_t)n0 * IN_F;
    const bf16* B1 = B + (size_t)(n0 + 128) * IN_F;

    f32x4 acc[8][4];
#pragma unroll
    for (int m = 0; m < 8; ++m)
#pragma unroll
        for (int n = 0; n < 4; ++n) acc[m][n] = (f32x4){0.f, 0.f, 0.f, 0.f};

    bf16x8 af0[4][2], af1[4][2], bfr0[2][2], bfr1[2][2];

    // ---- prologue: tile0 fully + tile1 {Ah0, Ah1, Bh0}; 14 loads in flight
    stage_half(A0,      sm + 0,     wave, lane);   // A(0) h0
    stage_half(A1,      sm + 16384, wave, lane);   // A(0) h1
    stage_half(B0,      sm + 32768, wave, lane);   // B(0) h0
    stage_half(B1,      sm + 49152, wave, lane);   // B(0) h1
    stage_half(A0 + 64, sm + 65536, wave, lane);   // A(1) h0
    stage_half(A1 + 64, sm + 81920, wave, lane);   // A(1) h1
    stage_half(B0 + 64, sm + 98304, wave, lane);   // B(1) h0
    VMCNT6();          // tile0 landed; tile1's 3 halves stay in flight
    BARRIER();
    // pre-read P1's fragments (buf0 t0) — P1's LGKM0 covers them
    LDA_SET(af0, 0, 0);
    LDB_SET(bfr0, 0, 0);

    for (int i = 0; i < 32; ++i) {
        const int t1 = 2 * i + 1;
        const int t2 = 2 * i + 2;
        const int t3 = 2 * i + 3;
        const bool gg = (i < 31);

        // ---- P1: MFMA t0 (MH0,NH0); stage buf1.Bh1(t1); pre-read af1.
        stage_half(B1 + t1 * 64, sm + 114688, wave, lane);
        LGKM0();
        MMA_Q(af0, bfr0, 0, 0);
        LDA_SET(af1, 0, 1);                                      // for P2
        BARRIER();
        // ---- P2: (MH1,NH0); buf0.Ah0 free (read prev P8, 2 barriers ago) -> stage.
        if (gg) stage_half(A0 + t2 * 64, sm + 0, wave, lane);
        LGKM0();
        MMA_Q(af1, bfr0, 1, 0);
        LDB_SET(bfr1, 0, 1);                                     // for P3
        BARRIER();
        // ---- P3: (MH0,NH1); buf0.Ah1 free (last t0 read at P2) -> stage.
        if (gg) stage_half(A1 + t2 * 64, sm + 16384, wave, lane);
        LGKM0();
        MMA_Q(af0, bfr1, 0, 1);
        BARRIER();
        // ---- P4: (MH1,NH1); buf0.Bh0 free (read prev P8) -> stage.
        if (gg) stage_half(B0 + t2 * 64, sm + 32768, wave, lane);
        LGKM0();
        MMA_Q(af1, bfr1, 1, 1);
        if (gg) { VMCNT6(); } else { VMCNT0(); }   // tile t1 fully landed
        LDA_SET(af0, 1, 0);                                      // for P5 (buf1)
        LDB_SET(bfr0, 1, 0);
        BARRIER();

        // ---- P5: t1 (buf1) (MH0,NH0); buf0.Bh1 free (read P2) -> stage.
        if (gg) stage_half(B1 + t2 * 64, sm + 49152, wave, lane);
        LGKM0();
        MMA_Q(af0, bfr0, 0, 0);
        LDA_SET(af1, 1, 1);                                      // for P6
        BARRIER();
        // ---- P6: (MH1,NH0); buf1.Ah0 free (read P4) -> stage.
        if (gg) stage_half(A0 + t3 * 64, sm + 65536, wave, lane);
        LGKM0();
        MMA_Q(af1, bfr0, 1, 0);
        LDB_SET(bfr1, 1, 1);                                     // for P7
        BARRIER();
        // ---- P7: (MH0,NH1); buf1.Ah1 free (read P5) -> stage.
        if (gg) stage_half(A1 + t3 * 64, sm + 81920, wave, lane);
        LGKM0();
        MMA_Q(af0, bfr1, 0, 1);
        BARRIER();
        // ---- P8: (MH1,NH1); buf1.Bh0 free (read P4) -> stage.
        if (gg) stage_half(B0 + t3 * 64, sm + 98304, wave, lane);
        LGKM0();
        MMA_Q(af1, bfr1, 1, 1);
        if (gg) { VMCNT6(); } else { VMCNT0(); }   // tile t2 fully landed
        if (gg) {
            LDA_SET(af0, 0, 0);                                  // for next-iter P1
            LDB_SET(bfr0, 0, 0);
        }
        BARRIER();
    }

    // ---- epilogue: C/D layout col = lane&15, row = (lane>>4)*4 + reg
    const int crow_base = m0 + wr * 64 + lq * 4;
    const int ccol_base = n0 + wc * 32 + l15;
#pragma unroll
    for (int n = 0; n < 4; ++n) {
        const int NH = n >> 1, n2 = n & 1;
        const int col = ccol_base + NH * 128 + n2 * 16;
        float bv = bias[col];
#pragma unroll
        for (int m = 0; m < 8; ++m) {
            const int MH = m >> 2, m4 = m & 3;
            const int row = crow_base + MH * 128 + m4 * 16;
#pragma unroll
            for (int r = 0; r < 4; ++r)
                C[(size_t)(row + r) * OUT_F + col] = acc[m][n][r] + bv;
        }
    }
}

// ---------------- fallback: fp32 tiled GEMM with on-the-fly dequant (ws too small)
__global__ __launch_bounds__(256) void fallback_gemm(const float* __restrict__ x,
                                                     const int* __restrict__ qweight,
                                                     const float* __restrict__ scales,
                                                     const int* __restrict__ qzeros,
                                                     const float* __restrict__ bias,
                                                     float* __restrict__ out) {
    __shared__ float Asf[64][65];
    __shared__ float Bsf[64][65];
    int bm = blockIdx.x >> 6;
    int bn = blockIdx.x & 63;
    int m0 = bm * 64, n0 = bn * 64;
    int t  = threadIdx.x;
    int tr = t >> 4, tc = t & 15;
    float acc[4][4] = {};
    for (int kt = 0; kt < IN_F; kt += 64) {
#pragma unroll
        for (int i = 0; i < 4; ++i) {
            int idx = t + i * 256;
            int r = idx >> 4, c4 = idx & 15;
            float4 v = *reinterpret_cast<const float4*>(x + (size_t)(m0 + r) * IN_F + kt + c4 * 4);
            Asf[r][c4 * 4 + 0] = v.x; Asf[r][c4 * 4 + 1] = v.y;
            Asf[r][c4 * 4 + 2] = v.z; Asf[r][c4 * 4 + 3] = v.w;
        }
#pragma unroll
        for (int i = 0; i < 2; ++i) {
            int idx = t + i * 256;
            int r = idx >> 3, k8 = idx & 7;
            int kk = kt + k8 * 8;
            int o  = n0 + r;
            int qw = qweight[(size_t)o * (IN_F / 8) + (kk >> 3)];
            int g  = kk >> 7;
            float s = scales[g * OUT_F + o];
            float z = (float)qzeros[g * OUT_F + o];
#pragma unroll
            for (int b = 0; b < 8; ++b)
                Bsf[r][k8 * 8 + b] = ((float)((qw >> (4 * b)) & 15) - z) * s;
        }
        __syncthreads();
#pragma unroll 8
        for (int k = 0; k < 64; ++k) {
            float a[4], bb[4];
#pragma unroll
            for (int i = 0; i < 4; ++i) a[i] = Asf[tr * 4 + i][k];
#pragma unroll
            for (int j = 0; j < 4; ++j) bb[j] = Bsf[tc * 4 + j][k];
#pragma unroll
            for (int i = 0; i < 4; ++i)
#pragma unroll
                for (int j = 0; j < 4; ++j) acc[i][j] += a[i] * bb[j];
        }
        __syncthreads();
    }
#pragma unroll
    for (int i = 0; i < 4; ++i) {
        int row = m0 + tr * 4 + i;
#pragma unroll
        for (int j = 0; j < 4; ++j) {
            int col = n0 + tc * 4 + j;
            out[(size_t)row * OUT_F + col] = acc[i][j] + bias[col];
        }
    }
}

extern "C" void kernel_launch(void* const* d_in, const int* in_sizes, int n_in,
                              void* d_out, int out_size, void* d_ws, size_t ws_size,
                              hipStream_t stream) {
    (void)in_sizes; (void)n_in; (void)out_size;
    const float* x       = (const float*)d_in[0];
    const int*   qweight = (const int*)d_in[1];
    const float* scales  = (const float*)d_in[2];
    const int*   qzeros  = (const int*)d_in[3];
    const float* bias    = (const float*)d_in[4];
    float* out = (float*)d_out;

    const size_t needW = (size_t)OUT_F * IN_F * sizeof(bf16);   // 32 MB
    const size_t needX = (size_t)M_TOTAL * IN_F * sizeof(bf16); // 64 MB

    if (ws_size >= needW + needX) {
        bf16* Wb = (bf16*)d_ws;
        bf16* Xb = (bf16*)((char*)d_ws + needW);
        // fused prep: 8192 dequant blocks + 16384 cvt blocks
        prep<<<8192 + 16384, 256, 0, stream>>>(qweight, scales, qzeros, Wb, x, Xb);
        gemm256<<<(M_TOTAL / 256) * (OUT_F / 256), 512, 131072, stream>>>(Xb, Wb, bias, out);
    } else {
        fallback_gemm<<<(M_TOTAL / 64) * (OUT_F / 64), 256, 0, stream>>>(
            x, qweight, scales, qzeros, bias, out);
    }
}